// Round 3
// baseline (300.907 us; speedup 1.0000x reference)
//
#include <hip/hip_runtime.h>

#define N 20000
#define E 200000
#define IN 128
#define OUT 128
#define NB 8
#define SI 16
#define SO 16
#define R 230
#define T 365

// Scratch in module .bss. d_ws untouched; kernel_launch does kernel launches
// only (graph-capture safe).
__device__ float g_W_t[(size_t)R * NB * SO * SI]; // W transposed: [r][b][ol][i]
__device__ float g_msg[(size_t)E * OUT];          // messages, dst-sorted order
__device__ int   g_cnt_d[N];                      // in-degree
__device__ int   g_off_d[N];                      // dst segment offsets
__device__ int   g_cur_d[N];
__device__ int   g_cnt_r[R * 16];                 // line-padded (contention)
__device__ int   g_cur_r[R * 16];
__device__ int   g_pos[E];                        // e -> dst-sorted position
__device__ int   g_eid_r[E];                      // edge ids sorted by relation
__device__ int   g_total_d;
__device__ int   g_total_r;

// Transpose W into [r][b][ol][i] (contiguous i -> 4x float4 register loads)
// and zero all counters.
__global__ void prep_kernel(const float* __restrict__ weight) {
    int t = blockIdx.x * blockDim.x + threadIdx.x;
    if (t < R * NB * SO * SI) {
        int r  = t >> 11;
        int b  = (t >> 8) & 7;
        int ol = (t >> 4) & 15;
        int i  = t & 15;
        g_W_t[t] = weight[(long)r * 2048 + b * 256 + i * 16 + ol];
    }
    if (t < N) g_cnt_d[t] = 0;
    if (t < R * 16) g_cnt_r[t] = 0;
    if (t == 0) { g_total_d = 0; g_total_r = 0; }
}

// Histograms: dst direct (low contention), relation via LDS aggregation.
__global__ __launch_bounds__(256) void hist_kernel(
        const int* __restrict__ edge_dst,
        const int* __restrict__ edge_type) {
    __shared__ int lh[R];
    for (int j = threadIdx.x; j < R; j += 256) lh[j] = 0;
    __syncthreads();
    for (long e = (long)blockIdx.x * blockDim.x + threadIdx.x; e < E;
         e += (long)gridDim.x * blockDim.x) {
        atomicAdd(&g_cnt_d[edge_dst[e]], 1);
        atomicAdd(&lh[edge_type[e]], 1);
    }
    __syncthreads();
    for (int j = threadIdx.x; j < R; j += 256)
        if (lh[j]) atomicAdd(&g_cnt_r[j * 16], lh[j]);
}

// Wave-aggregated bump allocation: one global atomic per wave (not per
// element). Segment order is irrelevant; only per-segment contiguity matters.
// Flattened index space: [0, 20032) -> dst (wave-aligned pad), [20032, +256) -> rel.
__global__ __launch_bounds__(256) void alloc_kernel() {
    int idx  = blockIdx.x * blockDim.x + threadIdx.x;
    int lane = threadIdx.x & 63;
    const int NPAD = 20032;                       // 313 waves, wave-aligned
    if (idx < NPAD) {
        int c = (idx < N) ? g_cnt_d[idx] : 0;
        int x = c;
        for (int d = 1; d < 64; d <<= 1) {
            int y = __shfl_up(x, d);
            if (lane >= d) x += y;
        }
        int base = 0;
        if (lane == 63) base = atomicAdd(&g_total_d, x);
        base = __shfl(base, 63);
        if (idx < N) {
            int off = base + x - c;
            g_off_d[idx] = off;
            g_cur_d[idx] = off;
        }
    } else if (idx < NPAD + 256) {
        int j = idx - NPAD;
        int c = (j < R) ? g_cnt_r[j * 16] : 0;
        int x = c;
        for (int d = 1; d < 64; d <<= 1) {
            int y = __shfl_up(x, d);
            if (lane >= d) x += y;
        }
        int base = 0;
        if (lane == 63) base = atomicAdd(&g_total_r, x);
        base = __shfl(base, 63);
        if (j < R) g_cur_r[j * 16] = base + x - c;
    }
}

__global__ void scatter_kernel(const int* __restrict__ edge_dst,
                               const int* __restrict__ edge_type) {
    int e = blockIdx.x * blockDim.x + threadIdx.x;
    if (e < E) {
        g_pos[e] = atomicAdd(&g_cur_d[edge_dst[e]], 1);
        int pr = atomicAdd(&g_cur_r[edge_type[e] * 16], 1);
        g_eid_r[pr] = e;
    }
}

// Relation-run message kernel. 256 threads = 2 groups x 128 features; each
// group owns 64 consecutive r-sorted edges, so W[r] lives in 16 registers
// (reloaded only at run boundaries, ~7% of groups). 2-deep software pipeline:
// meta prefetched 2 ahead, h-row issued 1 ahead. msg written at the edge's
// dst-sorted position -> the sum kernel streams contiguously.
__global__ __launch_bounds__(256) void msg_kernel(
        const float* __restrict__ h,
        const float* __restrict__ edge_norm,
        const int* __restrict__ edge_src,
        const int* __restrict__ edge_type) {
    const int tid = threadIdx.x;
    const int grp = tid >> 7;            // 0,1
    const int o   = tid & 127;
    const int b   = o >> 4;
    const int ol  = o & 15;

    int lo = blockIdx.x * 128 + grp * 64;
    int hi = lo + 64; if (hi > E) hi = E;
    if (lo >= hi) return;

    int rcur = -1;
    float4 w0, w1, w2, w3;

    // meta for edge k (cur) and k+1 (nxt)
    int   e0 = g_eid_r[lo];
    int   s0 = edge_src[e0];
    int   r0 = edge_type[e0];
    float n0 = edge_norm[e0];
    int   p0 = g_pos[e0];
    // h regs for edge k
    const float4* hp = reinterpret_cast<const float4*>(h + (long)s0 * IN + b * SI);
    float4 hA0 = hp[0], hA1 = hp[1], hA2 = hp[2], hA3 = hp[3];

    int s1 = 0, r1 = 0, p1 = 0; float n1 = 0.f;
    if (lo + 1 < hi) {
        int e1 = g_eid_r[lo + 1];
        s1 = edge_src[e1]; r1 = edge_type[e1];
        n1 = edge_norm[e1]; p1 = g_pos[e1];
    }

    for (int k = lo; k < hi; ++k) {
        // prefetch meta for k+2
        int s2 = 0, r2 = 0, p2 = 0; float n2 = 0.f;
        if (k + 2 < hi) {
            int e2 = g_eid_r[k + 2];
            s2 = edge_src[e2]; r2 = edge_type[e2];
            n2 = edge_norm[e2]; p2 = g_pos[e2];
        }
        // issue h loads for k+1 (meta already resident)
        float4 hB0, hB1, hB2, hB3;
        if (k + 1 < hi) {
            const float4* hq =
                reinterpret_cast<const float4*>(h + (long)s1 * IN + b * SI);
            hB0 = hq[0]; hB1 = hq[1]; hB2 = hq[2]; hB3 = hq[3];
        }
        // W regs for current edge's relation (group-uniform branch, rare)
        if (r0 != rcur) {
            const float4* wp = reinterpret_cast<const float4*>(
                g_W_t + (long)r0 * 2048 + b * 256 + ol * 16);
            w0 = wp[0]; w1 = wp[1]; w2 = wp[2]; w3 = wp[3];
            rcur = r0;
        }
        float m0 = 0.f, m1 = 0.f;
        m0 = fmaf(hA0.x, w0.x, m0); m0 = fmaf(hA0.y, w0.y, m0);
        m0 = fmaf(hA0.z, w0.z, m0); m0 = fmaf(hA0.w, w0.w, m0);
        m1 = fmaf(hA1.x, w1.x, m1); m1 = fmaf(hA1.y, w1.y, m1);
        m1 = fmaf(hA1.z, w1.z, m1); m1 = fmaf(hA1.w, w1.w, m1);
        m0 = fmaf(hA2.x, w2.x, m0); m0 = fmaf(hA2.y, w2.y, m0);
        m0 = fmaf(hA2.z, w2.z, m0); m0 = fmaf(hA2.w, w2.w, m0);
        m1 = fmaf(hA3.x, w3.x, m1); m1 = fmaf(hA3.y, w3.y, m1);
        m1 = fmaf(hA3.z, w3.z, m1); m1 = fmaf(hA3.w, w3.w, m1);
        g_msg[(long)p0 * OUT + o] = n0 * (m0 + m1);

        hA0 = hB0; hA1 = hB1; hA2 = hB2; hA3 = hB3;
        s0 = s1; r0 = r1; n0 = n1; p0 = p1;
        s1 = s2; r1 = r2; n1 = n2; p1 = p2;
    }
}

// Fused segment-sum + self-loop GEMM + epilogue + time-embedding gather.
// 8 nodes/block, 128 threads (thread = out feature) -> 2500 blocks.
__global__ __launch_bounds__(128) void node_kernel(
        const float* __restrict__ h,
        const float* __restrict__ node_norm,
        const float* __restrict__ h_bias,
        const float* __restrict__ loop_weight,
        const float* __restrict__ time_embed,
        const int* __restrict__ time_idx,
        float* __restrict__ out) {
    __shared__ float hsm[IN * 8];        // hsm[i*8 + nl]
    const int o    = threadIdx.x;
    const int base = blockIdx.x * 8;

    for (int k = o; k < 8 * IN; k += 128) {
        int nl = k >> 7;
        int i  = k & 127;
        hsm[i * 8 + nl] = h[(long)(base + nl) * IN + i];
    }
    __syncthreads();

    // contiguous segment sums (msg already in dst order)
    float acc[8];
#pragma unroll
    for (int nl = 0; nl < 8; ++nl) {
        int n  = base + nl;
        int st = g_off_d[n];
        int cn = g_cnt_d[n];
        float a0 = 0.f, a1 = 0.f;
        int k = 0;
        for (; k + 1 < cn; k += 2) {
            a0 += g_msg[(long)(st + k) * OUT + o];
            a1 += g_msg[(long)(st + k + 1) * OUT + o];
        }
        if (k < cn) a0 += g_msg[(long)(st + k) * OUT + o];
        acc[nl] = (a0 + a1) * node_norm[n];
    }

    // self-loop GEMM: 8-wide w-load pipeline, float4 LDS broadcasts
    float sl[8];
#pragma unroll
    for (int nl = 0; nl < 8; ++nl) sl[nl] = 0.f;

    for (int i0 = 0; i0 < IN; i0 += 8) {
        float w[8];
#pragma unroll
        for (int j = 0; j < 8; ++j)
            w[j] = loop_weight[(long)(i0 + j) * OUT + o];
#pragma unroll
        for (int j = 0; j < 8; ++j) {
            const float* row = &hsm[(i0 + j) * 8];
            float4 p0 = *reinterpret_cast<const float4*>(row);
            float4 p1 = *reinterpret_cast<const float4*>(row + 4);
            sl[0] = fmaf(p0.x, w[j], sl[0]); sl[1] = fmaf(p0.y, w[j], sl[1]);
            sl[2] = fmaf(p0.z, w[j], sl[2]); sl[3] = fmaf(p0.w, w[j], sl[3]);
            sl[4] = fmaf(p1.x, w[j], sl[4]); sl[5] = fmaf(p1.y, w[j], sl[5]);
            sl[6] = fmaf(p1.z, w[j], sl[6]); sl[7] = fmaf(p1.w, w[j], sl[7]);
        }
    }

    const float bias = h_bias[o];
#pragma unroll
    for (int nl = 0; nl < 8; ++nl) {
        int n = base + nl;
        float v = acc[nl] + bias + sl[nl];
        out[(long)n * OUT + o] = fmaxf(v, 0.f);
        out[(long)N * OUT + (long)n * IN + o] =
            time_embed[(long)time_idx[n] * IN + o];
    }
}

extern "C" void kernel_launch(void* const* d_in, const int* in_sizes, int n_in,
                              void* d_out, int out_size, void* d_ws, size_t ws_size,
                              hipStream_t stream) {
    const float* h           = (const float*)d_in[0];
    const float* edge_norm   = (const float*)d_in[1];
    const float* node_norm   = (const float*)d_in[2];
    const float* weight      = (const float*)d_in[3];
    const float* h_bias      = (const float*)d_in[4];
    const float* loop_weight = (const float*)d_in[5];
    const float* time_embed  = (const float*)d_in[6];
    const int*   edge_src    = (const int*)d_in[7];
    const int*   edge_dst    = (const int*)d_in[8];
    const int*   edge_type   = (const int*)d_in[9];
    const int*   time_idx    = (const int*)d_in[10];
    float* out = (float*)d_out;

    prep_kernel<<<(R * NB * SO * SI + 255) / 256, 256, 0, stream>>>(weight);
    hist_kernel<<<200, 256, 0, stream>>>(edge_dst, edge_type);
    alloc_kernel<<<(20032 + 256 + 255) / 256, 256, 0, stream>>>();
    scatter_kernel<<<(E + 255) / 256, 256, 0, stream>>>(edge_dst, edge_type);
    msg_kernel<<<(E + 127) / 128, 256, 0, stream>>>(h, edge_norm,
                                                    edge_src, edge_type);
    node_kernel<<<N / 8, 128, 0, stream>>>(h, node_norm, h_bias, loop_weight,
                                           time_embed, time_idx, out);
}

// Round 4
// 227.901 us; speedup vs baseline: 1.3203x; 1.3203x over previous
//
#include <hip/hip_runtime.h>

#define N 20000
#define E 200000
#define IN 128
#define OUT 128
#define NB 8
#define SI 16
#define SO 16
#define R 230
#define T 365

// Scratch in module .bss. d_ws untouched; kernel_launch does kernel launches
// only (graph-capture safe).
__device__ float g_W_t[(size_t)R * NB * SO * SI]; // W transposed: [r][b][ol][i]
__device__ float g_msg[(size_t)E * OUT];          // messages, dst-sorted order
__device__ int   g_cnt_d[N];                      // in-degree
__device__ int   g_off_d[N];                      // dst segment offsets
__device__ int   g_cur_d[N];
__device__ int   g_cnt_r[R * 16];                 // line-padded (contention)
__device__ int   g_cur_r[R * 16];
__device__ int   g_pos[E];                        // e -> dst-sorted position
__device__ int   g_eid_r[E];                      // edge ids sorted by relation
__device__ int   g_total_d;
__device__ int   g_total_r;

// W transpose into [r][b][ol][i] (contiguous i) + zero all counters.
__global__ void init_kernel(const float* __restrict__ weight) {
    int t = blockIdx.x * blockDim.x + threadIdx.x;
    if (t < R * NB * SO * SI) {
        int r  = t >> 11;
        int b  = (t >> 8) & 7;
        int ol = (t >> 4) & 15;
        int i  = t & 15;
        g_W_t[t] = weight[(long)r * 2048 + b * 256 + i * 16 + ol];
    }
    if (t < N) g_cnt_d[t] = 0;
    if (t < R * 16) g_cnt_r[t] = 0;
    if (t == 0) { g_total_d = 0; g_total_r = 0; }
}

// Both histograms in one pass: dst direct (20K addresses, low contention),
// relation via LDS aggregation (230 hot addresses).
__global__ __launch_bounds__(256) void hist_kernel(
        const int* __restrict__ edge_dst,
        const int* __restrict__ edge_type) {
    __shared__ int lh[R];
    for (int j = threadIdx.x; j < R; j += 256) lh[j] = 0;
    __syncthreads();
    for (long e = (long)blockIdx.x * blockDim.x + threadIdx.x; e < E;
         e += (long)gridDim.x * blockDim.x) {
        atomicAdd(&g_cnt_d[edge_dst[e]], 1);
        atomicAdd(&lh[edge_type[e]], 1);
    }
    __syncthreads();
    for (int j = threadIdx.x; j < R; j += 256)
        if (lh[j]) atomicAdd(&g_cnt_r[j * 16], lh[j]);
}

// Wave-aggregated bump allocation (one global atomic per wave).
__global__ __launch_bounds__(256) void alloc_kernel() {
    int idx  = blockIdx.x * blockDim.x + threadIdx.x;
    int lane = threadIdx.x & 63;
    const int NPAD = 20032;
    if (idx < NPAD) {
        int c = (idx < N) ? g_cnt_d[idx] : 0;
        int x = c;
        for (int d = 1; d < 64; d <<= 1) {
            int y = __shfl_up(x, d);
            if (lane >= d) x += y;
        }
        int base = 0;
        if (lane == 63) base = atomicAdd(&g_total_d, x);
        base = __shfl(base, 63);
        if (idx < N) {
            int off = base + x - c;
            g_off_d[idx] = off;
            g_cur_d[idx] = off;
        }
    } else if (idx < NPAD + 256) {
        int j = idx - NPAD;
        int c = (j < R) ? g_cnt_r[j * 16] : 0;
        int x = c;
        for (int d = 1; d < 64; d <<= 1) {
            int y = __shfl_up(x, d);
            if (lane >= d) x += y;
        }
        int base = 0;
        if (lane == 63) base = atomicAdd(&g_total_r, x);
        base = __shfl(base, 63);
        if (j < R) g_cur_r[j * 16] = base + x - c;
    }
}

__global__ void scatter_kernel(const int* __restrict__ edge_dst,
                               const int* __restrict__ edge_type) {
    int e = blockIdx.x * blockDim.x + threadIdx.x;
    if (e < E) {
        g_pos[e] = atomicAdd(&g_cur_d[edge_dst[e]], 1);
        int pr = atomicAdd(&g_cur_r[edge_type[e] * 16], 1);
        g_eid_r[pr] = e;
    }
}

// Block-pipelined message kernel. Block = 64 consecutive r-sorted edges,
// 256 threads. Phase 1: cooperative metadata load (one latency round / 64
// edges). Phase 2: cooperative h-row gather into LDS (8 independent float4
// loads per thread — no dependent chains, MLP does the latency hiding).
// Phase 3: compute from LDS broadcasts; W[r] in 16 registers, loaded once
// per block on the single-relation fast path (~93% of blocks).
// E = 3125 * 64 exactly — no tail handling needed.
__global__ __launch_bounds__(256) void msg_kernel(
        const float* __restrict__ h,
        const float* __restrict__ edge_norm,
        const int* __restrict__ edge_src,
        const int* __restrict__ edge_type) {
    __shared__ __attribute__((aligned(16))) float hsm[64 * 132]; // pad: 2-way max
    __shared__ int   ssrc[64], stype[64], spos[64];
    __shared__ float snorm[64];

    const int tid = threadIdx.x;
    const int lo  = blockIdx.x * 64;

    if (tid < 64) {
        int e = g_eid_r[lo + tid];
        ssrc[tid]  = edge_src[e];
        stype[tid] = edge_type[e];
        snorm[tid] = edge_norm[e];
        spos[tid]  = g_pos[e];
    }
    __syncthreads();

    // gather 64 h-rows: 4 threads per row, 8 float4 each (64B-coalesced)
    {
        const int row = tid >> 2;
        const int c0  = (tid & 3) * 4;
        const float* hp = h + (long)ssrc[row] * IN;
        float* dst = &hsm[row * 132];
#pragma unroll
        for (int j = 0; j < 8; ++j) {
            float4 v = *reinterpret_cast<const float4*>(hp + c0 + 16 * j);
            *reinterpret_cast<float4*>(dst + c0 + 16 * j) = v;
        }
    }
    __syncthreads();

    const int slot = tid >> 7;           // 0,1
    const int o    = tid & 127;
    const int b    = o >> 4;
    const int ol   = o & 15;

#define MSG_BODY(K, W0, W1, W2, W3)                                          \
    {                                                                        \
        const float* hrow = &hsm[(K) * 132 + b * 16];                        \
        float4 h0 = *reinterpret_cast<const float4*>(hrow);                  \
        float4 h1 = *reinterpret_cast<const float4*>(hrow + 4);              \
        float4 h2 = *reinterpret_cast<const float4*>(hrow + 8);              \
        float4 h3 = *reinterpret_cast<const float4*>(hrow + 12);             \
        float m0 = 0.f, m1 = 0.f;                                            \
        m0 = fmaf(h0.x, W0.x, m0); m0 = fmaf(h0.y, W0.y, m0);                \
        m0 = fmaf(h0.z, W0.z, m0); m0 = fmaf(h0.w, W0.w, m0);                \
        m1 = fmaf(h1.x, W1.x, m1); m1 = fmaf(h1.y, W1.y, m1);                \
        m1 = fmaf(h1.z, W1.z, m1); m1 = fmaf(h1.w, W1.w, m1);                \
        m0 = fmaf(h2.x, W2.x, m0); m0 = fmaf(h2.y, W2.y, m0);                \
        m0 = fmaf(h2.z, W2.z, m0); m0 = fmaf(h2.w, W2.w, m0);                \
        m1 = fmaf(h3.x, W3.x, m1); m1 = fmaf(h3.y, W3.y, m1);                \
        m1 = fmaf(h3.z, W3.z, m1); m1 = fmaf(h3.w, W3.w, m1);                \
        g_msg[(long)spos[K] * OUT + o] = snorm[K] * (m0 + m1);               \
    }

    if (stype[0] == stype[63]) {
        // single-relation block: W loaded once, clean unrolled loop
        const float4* wp = reinterpret_cast<const float4*>(
            g_W_t + (long)stype[0] * 2048 + b * 256 + ol * 16);
        float4 w0 = wp[0], w1 = wp[1], w2 = wp[2], w3 = wp[3];
#pragma unroll 4
        for (int k = slot; k < 64; k += 2)
            MSG_BODY(k, w0, w1, w2, w3)
    } else {
        int rcur = -1;
        float4 w0, w1, w2, w3;
        for (int k = slot; k < 64; k += 2) {
            int r = stype[k];
            if (r != rcur) {
                const float4* wp = reinterpret_cast<const float4*>(
                    g_W_t + (long)r * 2048 + b * 256 + ol * 16);
                w0 = wp[0]; w1 = wp[1]; w2 = wp[2]; w3 = wp[3];
                rcur = r;
            }
            MSG_BODY(k, w0, w1, w2, w3)
        }
    }
#undef MSG_BODY
}

// Fused segment-sum + self-loop GEMM + epilogue + time-embedding gather.
// 8 nodes/block, 128 threads (thread = out feature) -> 2500 blocks.
__global__ __launch_bounds__(128) void node_kernel(
        const float* __restrict__ h,
        const float* __restrict__ node_norm,
        const float* __restrict__ h_bias,
        const float* __restrict__ loop_weight,
        const float* __restrict__ time_embed,
        const int* __restrict__ time_idx,
        float* __restrict__ out) {
    __shared__ float hsm[IN * 8];        // hsm[i*8 + nl]
    const int o    = threadIdx.x;
    const int base = blockIdx.x * 8;

    for (int k = o; k < 8 * IN; k += 128) {
        int nl = k >> 7;
        int i  = k & 127;
        hsm[i * 8 + nl] = h[(long)(base + nl) * IN + i];
    }
    __syncthreads();

    // contiguous segment sums (msg already in dst order), 4-way partials
    float acc[8];
#pragma unroll
    for (int nl = 0; nl < 8; ++nl) {
        int n  = base + nl;
        int st = g_off_d[n];
        int cn = g_cnt_d[n];
        float a0 = 0.f, a1 = 0.f, a2 = 0.f, a3 = 0.f;
        const float* mp = g_msg + (long)st * OUT + o;
        int k = 0;
        for (; k + 3 < cn; k += 4) {
            a0 += mp[(long)(k + 0) * OUT];
            a1 += mp[(long)(k + 1) * OUT];
            a2 += mp[(long)(k + 2) * OUT];
            a3 += mp[(long)(k + 3) * OUT];
        }
        for (; k < cn; ++k) a0 += mp[(long)k * OUT];
        acc[nl] = ((a0 + a1) + (a2 + a3)) * node_norm[n];
    }

    // self-loop GEMM: 8-wide w-load pipeline, float4 LDS broadcasts
    float sl[8];
#pragma unroll
    for (int nl = 0; nl < 8; ++nl) sl[nl] = 0.f;

    for (int i0 = 0; i0 < IN; i0 += 8) {
        float w[8];
#pragma unroll
        for (int j = 0; j < 8; ++j)
            w[j] = loop_weight[(long)(i0 + j) * OUT + o];
#pragma unroll
        for (int j = 0; j < 8; ++j) {
            const float* row = &hsm[(i0 + j) * 8];
            float4 p0 = *reinterpret_cast<const float4*>(row);
            float4 p1 = *reinterpret_cast<const float4*>(row + 4);
            sl[0] = fmaf(p0.x, w[j], sl[0]); sl[1] = fmaf(p0.y, w[j], sl[1]);
            sl[2] = fmaf(p0.z, w[j], sl[2]); sl[3] = fmaf(p0.w, w[j], sl[3]);
            sl[4] = fmaf(p1.x, w[j], sl[4]); sl[5] = fmaf(p1.y, w[j], sl[5]);
            sl[6] = fmaf(p1.z, w[j], sl[6]); sl[7] = fmaf(p1.w, w[j], sl[7]);
        }
    }

    const float bias = h_bias[o];
#pragma unroll
    for (int nl = 0; nl < 8; ++nl) {
        int n = base + nl;
        float v = acc[nl] + bias + sl[nl];
        out[(long)n * OUT + o] = fmaxf(v, 0.f);
        out[(long)N * OUT + (long)n * IN + o] =
            time_embed[(long)time_idx[n] * IN + o];
    }
}

extern "C" void kernel_launch(void* const* d_in, const int* in_sizes, int n_in,
                              void* d_out, int out_size, void* d_ws, size_t ws_size,
                              hipStream_t stream) {
    const float* h           = (const float*)d_in[0];
    const float* edge_norm   = (const float*)d_in[1];
    const float* node_norm   = (const float*)d_in[2];
    const float* weight      = (const float*)d_in[3];
    const float* h_bias      = (const float*)d_in[4];
    const float* loop_weight = (const float*)d_in[5];
    const float* time_embed  = (const float*)d_in[6];
    const int*   edge_src    = (const int*)d_in[7];
    const int*   edge_dst    = (const int*)d_in[8];
    const int*   edge_type   = (const int*)d_in[9];
    const int*   time_idx    = (const int*)d_in[10];
    float* out = (float*)d_out;

    init_kernel<<<(R * NB * SO * SI + 255) / 256, 256, 0, stream>>>(weight);
    hist_kernel<<<400, 256, 0, stream>>>(edge_dst, edge_type);
    alloc_kernel<<<(20032 + 256 + 255) / 256, 256, 0, stream>>>();
    scatter_kernel<<<(E + 255) / 256, 256, 0, stream>>>(edge_dst, edge_type);
    msg_kernel<<<E / 64, 256, 0, stream>>>(h, edge_norm, edge_src, edge_type);
    node_kernel<<<N / 8, 128, 0, stream>>>(h, node_norm, h_bias, loop_weight,
                                           time_embed, time_idx, out);
}